// Round 1
// baseline (4575.428 us; speedup 1.0000x reference)
//
#include <hip/hip_runtime.h>
#include <math.h>

#define B_    1024
#define N_    128
#define D_    512
#define H_    8
#define DH_   64
#define DCOL_ 14

// ---------------- kernel 1: adjacency mask [H][N][N] -> d_ws ----------------
// adj_mask = 0 if edge kept, -10000 if masked.
// adj = (sigmoid(top+bias) > 0.5) && m!=n && m!=0  <=>  (top+bias > 0) && ...
__global__ __launch_bounds__(128) void mask_kernel(
    const float* __restrict__ col_head, const float* __restrict__ col_tail,
    const float* __restrict__ bias, float* __restrict__ mask)
{
  int h = blockIdx.x >> 7;
  int n = blockIdx.x & 127;
  int m = threadIdx.x;
  const float* ch = col_head + (h * N_ + n) * DCOL_;
  const float* ct = col_tail + (h * N_ + m) * DCOL_;
  float nh = 0.f, nt = 0.f, dot = 0.f;
#pragma unroll
  for (int k = 0; k < DCOL_; k++) {
    float a = ch[k], b = ct[k];
    nh += a * a; nt += b * b; dot += a * b;
  }
  float denom = fmaxf(sqrtf(nh), 1e-12f) * fmaxf(sqrtf(nt), 1e-12f);
  float top = dot / denom + bias[0];
  bool adj = (top > 0.f) && (m != n) && (m != 0);
  mask[(h * N_ + n) * N_ + m] = adj ? 0.f : -10000.f;
}

// ---------------- kernel 2: transpose W_out into d_ws ----------------
__global__ __launch_bounds__(256) void transpose_w(
    const float* __restrict__ w, float* __restrict__ wt)
{
  int idx = blockIdx.x * 256 + threadIdx.x;   // 0..262143
  int d = idx >> 9, k = idx & 511;
  wt[k * D_ + d] = w[idx];                    // wt[k][d] = W[d][k]
}

// ---------------- kernel 3: fused per-(b,h) attention ----------------
// projections (head + v) -> scores (*rel, /8, +mask) -> softmax -> fr_graph
// -> P@V -> out[b, n, h*64+d]  (pre-final-projection)
__global__ __launch_bounds__(256) void fused_attn(
    const float* __restrict__ x,
    const float* __restrict__ Wh, const float* __restrict__ bh,
    const float* __restrict__ Wv, const float* __restrict__ bv,
    const float* __restrict__ rel, const float* __restrict__ mask,
    float* __restrict__ out, float* __restrict__ fr)
{
  __shared__ float xs[N_][9];         // x K-slab, padded
  __shared__ float whs[DH_][9];
  __shared__ float wvs[DH_][9];
  __shared__ float fhs[N_][DH_ + 1];  // f_head; later reused as P half-tile
  __shared__ float fvs[N_][DH_ + 1];  // f_v
  __shared__ float rels[DH_];

  const int tid = threadIdx.x;
  const int tx = tid & 15, ty = tid >> 4;   // 16x16 thread grid
  const int b = blockIdx.x >> 3, h = blockIdx.x & 7;

  if (tid < DH_) rels[tid] = rel[h * DH_ + tid];

  const float* xb  = x  + (size_t)b * N_ * D_;
  const float* whr = Wh + (size_t)h * DH_ * D_;   // rows h*64..h*64+63
  const float* wvr = Wv + (size_t)h * DH_ * D_;

  // ---- phase 1: f_head / f_v projections ----
  float accH[8][4], accV[8][4];
#pragma unroll
  for (int i = 0; i < 8; i++)
#pragma unroll
    for (int j = 0; j < 4; j++) { accH[i][j] = 0.f; accV[i][j] = 0.f; }

  for (int k0 = 0; k0 < D_; k0 += 8) {
    __syncthreads();
    { // stage x slab: 128 rows x 8 k (1 float4 per thread)
      int n = tid >> 1, q = tid & 1;
      float4 v = *(const float4*)(xb + n * D_ + k0 + 4 * q);
      xs[n][4 * q + 0] = v.x; xs[n][4 * q + 1] = v.y;
      xs[n][4 * q + 2] = v.z; xs[n][4 * q + 3] = v.w;
    }
    if (tid < 128) { // stage W_head slab: 64 rows x 8 k
      int c = tid >> 1, q = tid & 1;
      float4 v = *(const float4*)(whr + c * D_ + k0 + 4 * q);
      whs[c][4 * q + 0] = v.x; whs[c][4 * q + 1] = v.y;
      whs[c][4 * q + 2] = v.z; whs[c][4 * q + 3] = v.w;
    } else {         // stage W_v slab
      int c = (tid - 128) >> 1, q = tid & 1;
      float4 v = *(const float4*)(wvr + c * D_ + k0 + 4 * q);
      wvs[c][4 * q + 0] = v.x; wvs[c][4 * q + 1] = v.y;
      wvs[c][4 * q + 2] = v.z; wvs[c][4 * q + 3] = v.w;
    }
    __syncthreads();
#pragma unroll
    for (int kk = 0; kk < 8; kk++) {
      float av[8], bhv[4], bvv[4];
#pragma unroll
      for (int i = 0; i < 8; i++) av[i] = xs[ty + 16 * i][kk];
#pragma unroll
      for (int j = 0; j < 4; j++) { bhv[j] = whs[tx + 16 * j][kk]; bvv[j] = wvs[tx + 16 * j][kk]; }
#pragma unroll
      for (int i = 0; i < 8; i++)
#pragma unroll
        for (int j = 0; j < 4; j++) {
          accH[i][j] += av[i] * bhv[j];
          accV[i][j] += av[i] * bvv[j];
        }
    }
  }

  float bhb[4], bvb[4];
#pragma unroll
  for (int j = 0; j < 4; j++) {
    bhb[j] = bh[h * DH_ + tx + 16 * j];
    bvb[j] = bv[h * DH_ + tx + 16 * j];
  }
#pragma unroll
  for (int i = 0; i < 8; i++)
#pragma unroll
    for (int j = 0; j < 4; j++) {
      fhs[ty + 16 * i][tx + 16 * j] = accH[i][j] + bhb[j];
      fvs[ty + 16 * i][tx + 16 * j] = accV[i][j] + bvb[j];
    }
  __syncthreads();

  // ---- phase 2: scores = (fh*rel) @ fh^T / 8 + mask, softmax ----
  float sc[8][8];
#pragma unroll
  for (int i = 0; i < 8; i++)
#pragma unroll
    for (int j = 0; j < 8; j++) sc[i][j] = 0.f;

  for (int k = 0; k < DH_; k++) {
    float rv = rels[k];
    float a[8], bb2[8];
#pragma unroll
    for (int i = 0; i < 8; i++) a[i] = fhs[ty + 16 * i][k] * rv;
#pragma unroll
    for (int j = 0; j < 8; j++) bb2[j] = fhs[tx + 16 * j][k];
#pragma unroll
    for (int i = 0; i < 8; i++)
#pragma unroll
      for (int j = 0; j < 8; j++) sc[i][j] += a[i] * bb2[j];
  }

  const float* mrow = mask + h * N_ * N_;
  float* frb = fr + (size_t)(b * H_ + h) * N_ * N_;
#pragma unroll
  for (int i = 0; i < 8; i++) {
    int r = ty + 16 * i;
    float rowmax = -3.0e38f;
#pragma unroll
    for (int j = 0; j < 8; j++) {
      float s = sc[i][j] * 0.125f + mrow[r * N_ + tx + 16 * j];
      sc[i][j] = s;
      rowmax = fmaxf(rowmax, s);
    }
#pragma unroll
    for (int d = 1; d < 16; d <<= 1) rowmax = fmaxf(rowmax, __shfl_xor(rowmax, d, 64));
    float rsum = 0.f;
#pragma unroll
    for (int j = 0; j < 8; j++) {
      float e = __expf(sc[i][j] - rowmax);
      sc[i][j] = e; rsum += e;
    }
#pragma unroll
    for (int d = 1; d < 16; d <<= 1) rsum += __shfl_xor(rsum, d, 64);
    float inv = 1.f / rsum;
#pragma unroll
    for (int j = 0; j < 8; j++) {
      float p = sc[i][j] * inv;
      sc[i][j] = p;
      frb[r * N_ + tx + 16 * j] = p;   // fr_graph output
    }
  }

  // ---- phase 3: out = P @ fv, P staged in halves over fhs ----
  float o[8][4];
#pragma unroll
  for (int i = 0; i < 8; i++)
#pragma unroll
    for (int c = 0; c < 4; c++) o[i][c] = 0.f;

#pragma unroll
  for (int half = 0; half < 2; half++) {
    __syncthreads();           // fhs free (scores done / prev half read done)
#pragma unroll
    for (int i = 0; i < 8; i++)
#pragma unroll
      for (int j = 0; j < 4; j++)
        fhs[ty + 16 * i][tx + 16 * j] = sc[i][half * 4 + j];  // P[r][m-64*half]
    __syncthreads();
    for (int kk = 0; kk < DH_; kk++) {
      float a[8], vv[4];
#pragma unroll
      for (int i = 0; i < 8; i++) a[i] = fhs[ty + 16 * i][kk];
#pragma unroll
      for (int c = 0; c < 4; c++) vv[c] = fvs[half * 64 + kk][tx + 16 * c];
#pragma unroll
      for (int i = 0; i < 8; i++)
#pragma unroll
        for (int c = 0; c < 4; c++) o[i][c] += a[i] * vv[c];
    }
  }

  float* ob = out + (size_t)b * N_ * D_ + h * DH_;
#pragma unroll
  for (int i = 0; i < 8; i++)
#pragma unroll
    for (int c = 0; c < 4; c++)
      ob[(size_t)(ty + 16 * i) * D_ + tx + 16 * c] = o[i][c];
}

// ---------------- kernel 4: final projection, in-place on d_out ----------------
// io rows m0..m0+31 : stage to LDS, out = a @ W_out^T + b, overwrite same rows.
__global__ __launch_bounds__(256) void out_proj(
    const float* __restrict__ wt, const float* __restrict__ bo,
    float* __restrict__ io)
{
  __shared__ float a_s[32][D_];
  __shared__ float w_l[8][D_];
  const int t = threadIdx.x;
  const size_t m0 = (size_t)blockIdx.x * 32;

#pragma unroll
  for (int p = 0; p < 16; p++) {      // stage 32x512 input rows
    int f = t + 256 * p;
    int n = f >> 7, q = f & 127;
    *(float4*)&a_s[n][4 * q] = *(const float4*)(io + (m0 + n) * D_ + 4 * q);
  }

  const int tx = t & 31, ty = t >> 5;  // 32 x 8 thread grid
  float o[4][16];
#pragma unroll
  for (int i = 0; i < 4; i++)
#pragma unroll
    for (int c = 0; c < 16; c++) o[i][c] = 0.f;

  for (int k0 = 0; k0 < D_; k0 += 8) {
    __syncthreads();                  // also covers initial a_s staging
#pragma unroll
    for (int p = 0; p < 4; p++) {     // stage W^T slab: 8 k x 512 d
      int f = t + 256 * p;
      int kk = f >> 7, q = f & 127;
      *(float4*)&w_l[kk][4 * q] = *(const float4*)(wt + (size_t)(k0 + kk) * D_ + 4 * q);
    }
    __syncthreads();
#pragma unroll
    for (int kk = 0; kk < 8; kk++) {
      float a[4];
#pragma unroll
      for (int i = 0; i < 4; i++) a[i] = a_s[ty * 4 + i][k0 + kk];
#pragma unroll
      for (int c = 0; c < 16; c++) {
        float w = w_l[kk][tx + 32 * c];
#pragma unroll
        for (int i = 0; i < 4; i++) o[i][c] += a[i] * w;
      }
    }
  }

#pragma unroll
  for (int c = 0; c < 16; c++) {
    float bb = bo[tx + 32 * c];
#pragma unroll
    for (int i = 0; i < 4; i++)
      io[(m0 + ty * 4 + i) * D_ + tx + 32 * c] = o[i][c] + bb;
  }
}

extern "C" void kernel_launch(void* const* d_in, const int* in_sizes, int n_in,
                              void* d_out, int out_size, void* d_ws, size_t ws_size,
                              hipStream_t stream)
{
  const float* x    = (const float*)d_in[0];
  const float* Whw  = (const float*)d_in[1];
  const float* Whb  = (const float*)d_in[2];
  const float* Wvw  = (const float*)d_in[3];
  const float* Wvb  = (const float*)d_in[4];
  const float* Wow  = (const float*)d_in[5];
  const float* Wob  = (const float*)d_in[6];
  const float* rel  = (const float*)d_in[7];
  const float* ch   = (const float*)d_in[8];
  const float* ct   = (const float*)d_in[9];
  const float* bias = (const float*)d_in[10];

  float* out  = (float*)d_out;                      // [B,N,D]
  float* fr   = out + (size_t)B_ * N_ * D_;         // [B,H,N,N]
  float* mask = (float*)d_ws;                       // [H,N,N]   (512 KB)
  float* wt   = mask + (size_t)H_ * N_ * N_;        // [D,D] W_out^T (1 MB)

  hipLaunchKernelGGL(mask_kernel, dim3(H_ * N_), dim3(128), 0, stream, ch, ct, bias, mask);
  hipLaunchKernelGGL(transpose_w, dim3(1024), dim3(256), 0, stream, Wow, wt);
  hipLaunchKernelGGL(fused_attn, dim3(B_ * H_), dim3(256), 0, stream,
                     x, Whw, Whb, Wvw, Wvb, rel, mask, out, fr);
  hipLaunchKernelGGL(out_proj, dim3((B_ * N_) / 32), dim3(256), 0, stream, wt, Wob, out);
}

// Round 3
// 1460.371 us; speedup vs baseline: 3.1331x; 3.1331x over previous
//
#include <hip/hip_runtime.h>
#include <math.h>

typedef _Float16 f16;
typedef f16 half8 __attribute__((ext_vector_type(8)));
typedef f16 half4 __attribute__((ext_vector_type(4)));
typedef f16 half2v __attribute__((ext_vector_type(2)));
typedef float f32x4 __attribute__((ext_vector_type(4)));

#define B_    1024
#define N_    128
#define D_    512
#define H_    8
#define DH_   64
#define DCOL_ 14

#define MFMA16(a,b,c) __builtin_amdgcn_mfma_f32_16x16x32_f16(a,b,c,0,0,0)

// ---------------- kernel 1: adjacency mask [H][N][N] (exact fp32) ----------------
__global__ __launch_bounds__(128) void mask_kernel(
    const float* __restrict__ col_head, const float* __restrict__ col_tail,
    const float* __restrict__ bias, float* __restrict__ mask)
{
  int h = blockIdx.x >> 7;
  int n = blockIdx.x & 127;
  int m = threadIdx.x;
  const float* ch = col_head + (h * N_ + n) * DCOL_;
  const float* ct = col_tail + (h * N_ + m) * DCOL_;
  float nh = 0.f, nt = 0.f, dot = 0.f;
#pragma unroll
  for (int k = 0; k < DCOL_; k++) {
    float a = ch[k], b = ct[k];
    nh += a * a; nt += b * b; dot += a * b;
  }
  float denom = fmaxf(sqrtf(nh), 1e-12f) * fmaxf(sqrtf(nt), 1e-12f);
  float top = dot / denom + bias[0];
  bool adj = (top > 0.f) && (m != n) && (m != 0);
  mask[(h * N_ + n) * N_ + m] = adj ? 0.f : -10000.f;
}

// ---------------- kernel 2: preconvert weights fp32 -> f16 ----------------
__global__ __launch_bounds__(256) void convert_w(
    const float* __restrict__ wh, const float* __restrict__ wv,
    const float* __restrict__ wo,
    f16* __restrict__ whh, f16* __restrict__ wvh, f16* __restrict__ woh)
{
  int i = (blockIdx.x * 256 + threadIdx.x) * 4;   // grid 256 -> covers 262144
  float4 a = *(const float4*)(wh + i);
  float4 b = *(const float4*)(wv + i);
  float4 c = *(const float4*)(wo + i);
  half4 ha = {(f16)a.x, (f16)a.y, (f16)a.z, (f16)a.w};
  half4 hb = {(f16)b.x, (f16)b.y, (f16)b.z, (f16)b.w};
  half4 hc = {(f16)c.x, (f16)c.y, (f16)c.z, (f16)c.w};
  *(half4*)(whh + i) = ha;
  *(half4*)(wvh + i) = hb;
  *(half4*)(woh + i) = hc;
}

// ---------------- kernel 3: fused per-(b,h) attention (MFMA f16) ----------------
// 256 threads = 4 waves. One 36KB LDS pool, time-shared (barrier-fenced):
//   phase1: xs[128][72] | wsl[128][72]      (x slab | [Wh;Wv] slab)
//   phase2: fhA[128][72] | fhB[128][72]     (rel-scaled fh | fh)
//   phase3: fvT[64][136] | Ph[128][72]      (fv^T | P half-tile)
__global__ __launch_bounds__(256) void fused_attn(
    const float* __restrict__ x, const float* __restrict__ bh,
    const float* __restrict__ bv, const float* __restrict__ rel,
    const float* __restrict__ mask,
    const f16* __restrict__ whh, const f16* __restrict__ wvh,
    float* __restrict__ out, float* __restrict__ fr)
{
  __shared__ __align__(16) f16 pool[18432];   // 36864 B
  f16* const xs  = pool;          // [128][72]
  f16* const wsl = pool + 9216;   // [128][72]

  const int t = threadIdx.x;
  const int lane = t & 63, w = t >> 6;
  const int l15 = lane & 15, lg = lane >> 4;
  const int wr = w >> 1, wc = w & 1;

  // XCD swizzle: 8 heads of one b stay on one XCD, consecutive in time
  const int g = blockIdx.x & 7, slot = blockIdx.x >> 3;
  const int b = (g << 7) + (slot >> 3), h = slot & 7;

  const float* xb = x + (size_t)b * (N_ * D_);
  const f32x4 z4 = {0.f, 0.f, 0.f, 0.f};

  // ---- phase 1: [fh | fv] = x @ [Wh;Wv]^T   (128x128, K=512) ----
  f32x4 acc[4][4];
#pragma unroll
  for (int i = 0; i < 4; i++)
#pragma unroll
    for (int j = 0; j < 4; j++) acc[i][j] = z4;

  for (int k0 = 0; k0 < 512; k0 += 64) {
    __syncthreads();
    // stage x slab 128x64 fp32 -> f16 (8 float4 / thread)
#pragma unroll
    for (int p = 0; p < 8; p++) {
      int c = t + 256 * p;
      int row = c >> 4, q = c & 15;
      float4 v = *(const float4*)(xb + row * 512 + k0 + 4 * q);
      half4 hv = {(f16)v.x, (f16)v.y, (f16)v.z, (f16)v.w};
      *(half4*)&xs[row * 72 + 4 * q] = hv;
    }
    // stage W slab: rows 0-63 = Wh[h*64+...], 64-127 = Wv[h*64+...] (4 half8 / thread)
#pragma unroll
    for (int p = 0; p < 4; p++) {
      int c = t + 256 * p;
      int row = c >> 3, q = c & 7;
      const f16* src = (row < 64)
          ? (whh + (size_t)(h * 64 + row) * 512 + k0 + 8 * q)
          : (wvh + (size_t)(h * 64 + row - 64) * 512 + k0 + 8 * q);
      *(half8*)&wsl[row * 72 + 8 * q] = *(const half8*)src;
    }
    __syncthreads();
#pragma unroll
    for (int kk = 0; kk < 64; kk += 32) {
      half8 af[4], bf[4];
#pragma unroll
      for (int rf = 0; rf < 4; rf++)
        af[rf] = *(const half8*)&xs[(64 * wr + 16 * rf + l15) * 72 + kk + 8 * lg];
#pragma unroll
      for (int fc = 0; fc < 4; fc++)
        bf[fc] = *(const half8*)&wsl[(64 * wc + 16 * fc + l15) * 72 + kk + 8 * lg];
#pragma unroll
      for (int rf = 0; rf < 4; rf++)
#pragma unroll
        for (int fc = 0; fc < 4; fc++)
          acc[rf][fc] = MFMA16(af[rf], bf[fc], acc[rf][fc]);
    }
  }
  __syncthreads();   // phase-1 LDS dead; pool becomes fhA/fhB

  f16* const fhA = pool;          // [128][72]  fh*rel
  f16* const fhB = pool + 9216;   // [128][72]  fh
  half2v vp[4][4][2];             // V-waves: packed fv (f16), freed acc

  if (wc == 0) {
    // H-waves own all 128 rows of fh: +bias, write plain & rel-scaled copies
#pragma unroll
    for (int fc = 0; fc < 4; fc++) {
      int d = 16 * fc + l15;
      float bb = bh[h * 64 + d];
      float rv = rel[h * 64 + d];
#pragma unroll
      for (int rf = 0; rf < 4; rf++)
#pragma unroll
        for (int j = 0; j < 4; j++) {
          int r = 64 * wr + 16 * rf + 4 * lg + j;
          float v = acc[rf][fc][j] + bb;
          fhB[r * 72 + d] = (f16)v;
          fhA[r * 72 + d] = (f16)(v * rv);
        }
    }
  } else {
    // V-waves: +bias, keep fv packed in registers (written to LDS after phase 2)
#pragma unroll
    for (int fc = 0; fc < 4; fc++) {
      int d = 16 * fc + l15;
      float bb = bv[h * 64 + d];
#pragma unroll
      for (int rf = 0; rf < 4; rf++) {
        half2v p0 = {(f16)(acc[rf][fc][0] + bb), (f16)(acc[rf][fc][1] + bb)};
        half2v p1 = {(f16)(acc[rf][fc][2] + bb), (f16)(acc[rf][fc][3] + bb)};
        vp[rf][fc][0] = p0;
        vp[rf][fc][1] = p1;
      }
    }
  }
  __syncthreads();

  // ---- phase 2: S = (fh*rel) @ fh^T / 8 + mask, softmax ----
  f32x4 s[2][8];
#pragma unroll
  for (int i = 0; i < 2; i++)
#pragma unroll
    for (int j = 0; j < 8; j++) s[i][j] = z4;

#pragma unroll
  for (int kk = 0; kk < 64; kk += 32) {
    half8 a2[2], b2[8];
#pragma unroll
    for (int rf = 0; rf < 2; rf++)
      a2[rf] = *(const half8*)&fhA[(32 * w + 16 * rf + l15) * 72 + kk + 8 * lg];
#pragma unroll
    for (int fc = 0; fc < 8; fc++)
      b2[fc] = *(const half8*)&fhB[(16 * fc + l15) * 72 + kk + 8 * lg];
#pragma unroll
    for (int rf = 0; rf < 2; rf++)
#pragma unroll
      for (int fc = 0; fc < 8; fc++)
        s[rf][fc] = MFMA16(a2[rf], b2[fc], s[rf][fc]);
  }

  const float* mrow = mask + h * (N_ * N_);
  float* frb = fr + (size_t)(b * H_ + h) * (N_ * N_);
#pragma unroll
  for (int rf = 0; rf < 2; rf++)
#pragma unroll
    for (int j = 0; j < 4; j++) {
      int r = 32 * w + 16 * rf + 4 * lg + j;
      float vals[8];
      float mx = -3.0e38f;
#pragma unroll
      for (int fc = 0; fc < 8; fc++) {
        float sv = s[rf][fc][j] * 0.125f + mrow[r * 128 + 16 * fc + l15];
        vals[fc] = sv;
        mx = fmaxf(mx, sv);
      }
#pragma unroll
      for (int d2 = 1; d2 < 16; d2 <<= 1) mx = fmaxf(mx, __shfl_xor(mx, d2, 64));
      float sum = 0.f;
#pragma unroll
      for (int fc = 0; fc < 8; fc++) {
        float e = __expf(vals[fc] - mx);
        vals[fc] = e; sum += e;
      }
#pragma unroll
      for (int d2 = 1; d2 < 16; d2 <<= 1) sum += __shfl_xor(sum, d2, 64);
      float inv = 1.f / sum;
#pragma unroll
      for (int fc = 0; fc < 8; fc++) {
        float p = vals[fc] * inv;
        s[rf][fc][j] = p;
        frb[r * 128 + 16 * fc + l15] = p;
      }
    }
  __syncthreads();   // all fhA/fhB reads done; pool becomes fvT/Ph

  // ---- phase 3: O = P @ fv  (K=128 in two halves of 64) ----
  f16* const fvT = pool;          // [64][136]
  f16* const Ph  = pool + 9216;   // [128][72]

  if (wc == 1) {
#pragma unroll
    for (int fc = 0; fc < 4; fc++) {
      int d = 16 * fc + l15;
#pragma unroll
      for (int rf = 0; rf < 4; rf++) {
        half2v p0 = vp[rf][fc][0], p1 = vp[rf][fc][1];
        half4 hv = {p0[0], p0[1], p1[0], p1[1]};
        *(half4*)&fvT[d * 136 + 64 * wr + 16 * rf + 4 * lg] = hv;
      }
    }
  }

  f32x4 o[2][4];
#pragma unroll
  for (int i = 0; i < 2; i++)
#pragma unroll
    for (int j = 0; j < 4; j++) o[i][j] = z4;

#pragma unroll
  for (int hk = 0; hk < 2; hk++) {
    // write this wave's P half-tile (own rows only)
#pragma unroll
    for (int rf = 0; rf < 2; rf++)
#pragma unroll
      for (int fc = 0; fc < 4; fc++)
#pragma unroll
        for (int j = 0; j < 4; j++)
          Ph[(32 * w + 16 * rf + 4 * lg + j) * 72 + fc * 16 + l15] =
              (f16)s[rf][fc + 4 * hk][j];
    __syncthreads();
#pragma unroll
    for (int kk = 0; kk < 64; kk += 32) {
      half8 ap[2], bp[4];
#pragma unroll
      for (int rf = 0; rf < 2; rf++)
        ap[rf] = *(const half8*)&Ph[(32 * w + 16 * rf + l15) * 72 + kk + 8 * lg];
#pragma unroll
      for (int fc = 0; fc < 4; fc++)
        bp[fc] = *(const half8*)&fvT[(16 * fc + l15) * 136 + 64 * hk + kk + 8 * lg];
#pragma unroll
      for (int rf = 0; rf < 2; rf++)
#pragma unroll
        for (int fc = 0; fc < 4; fc++)
          o[rf][fc] = MFMA16(ap[rf], bp[fc], o[rf][fc]);
    }
    __syncthreads();   // before half-1 rewrite of Ph
  }

  float* ob = out + (size_t)b * (N_ * D_) + h * 64;
#pragma unroll
  for (int rf = 0; rf < 2; rf++)
#pragma unroll
    for (int fc = 0; fc < 4; fc++)
#pragma unroll
      for (int j = 0; j < 4; j++)
        ob[(size_t)(32 * w + 16 * rf + 4 * lg + j) * 512 + 16 * fc + l15] =
            o[rf][fc][j];
}

// ---------------- kernel 4: final projection (MFMA f16), in-place ----------------
// 512 threads = 8 waves (2x4 grid of 64x128 wave tiles). BM=128, BN=512, BK=32.
// Each block owns rows [m0,m0+128) exclusively -> in-place safe.
__global__ __launch_bounds__(512) void out_proj(
    const f16* __restrict__ woh, const float* __restrict__ bo,
    float* __restrict__ io)
{
  __shared__ __align__(16) f16 a_s[128 * 40];
  __shared__ __align__(16) f16 b_s[512 * 40];
  const int t = threadIdx.x, lane = t & 63, w = t >> 6;
  const int l15 = lane & 15, lg = lane >> 4;
  const int wr = w >> 2, wc = w & 3;
  const size_t m0 = (size_t)blockIdx.x * 128;
  const f32x4 z4 = {0.f, 0.f, 0.f, 0.f};

  f32x4 acc[4][8];
#pragma unroll
  for (int i = 0; i < 4; i++)
#pragma unroll
    for (int j = 0; j < 8; j++) acc[i][j] = z4;

  for (int k0 = 0; k0 < 512; k0 += 32) {
    __syncthreads();
    // stage A: 128x32 fp32 -> f16
#pragma unroll
    for (int p = 0; p < 2; p++) {
      int c = t + 512 * p;
      int row = c >> 3, q = c & 7;
      float4 v = *(const float4*)(io + (m0 + row) * 512 + k0 + 4 * q);
      half4 hv = {(f16)v.x, (f16)v.y, (f16)v.z, (f16)v.w};
      *(half4*)&a_s[row * 40 + 4 * q] = hv;
    }
    // stage B: Wout 512x32 f16
#pragma unroll
    for (int p = 0; p < 4; p++) {
      int c = t + 512 * p;
      int row = c >> 2, q = c & 3;
      *(half8*)&b_s[row * 40 + 8 * q] =
          *(const half8*)(woh + (size_t)row * 512 + k0 + 8 * q);
    }
    __syncthreads();
    half8 af[4], bf[8];
#pragma unroll
    for (int rf = 0; rf < 4; rf++)
      af[rf] = *(const half8*)&a_s[(64 * wr + 16 * rf + l15) * 40 + 8 * lg];
#pragma unroll
    for (int fc = 0; fc < 8; fc++)
      bf[fc] = *(const half8*)&b_s[(128 * wc + 16 * fc + l15) * 40 + 8 * lg];
#pragma unroll
    for (int rf = 0; rf < 4; rf++)
#pragma unroll
      for (int fc = 0; fc < 8; fc++)
        acc[rf][fc] = MFMA16(af[rf], bf[fc], acc[rf][fc]);
  }

#pragma unroll
  for (int fc = 0; fc < 8; fc++) {
    float bb = bo[128 * wc + 16 * fc + l15];
#pragma unroll
    for (int rf = 0; rf < 4; rf++)
#pragma unroll
      for (int j = 0; j < 4; j++)
        io[(m0 + 64 * wr + 16 * rf + 4 * lg + j) * 512 + 128 * wc + 16 * fc + l15] =
            acc[rf][fc][j] + bb;
  }
}

extern "C" void kernel_launch(void* const* d_in, const int* in_sizes, int n_in,
                              void* d_out, int out_size, void* d_ws, size_t ws_size,
                              hipStream_t stream)
{
  const float* x    = (const float*)d_in[0];
  const float* Whw  = (const float*)d_in[1];
  const float* Whb  = (const float*)d_in[2];
  const float* Wvw  = (const float*)d_in[3];
  const float* Wvb  = (const float*)d_in[4];
  const float* Wow  = (const float*)d_in[5];
  const float* Wob  = (const float*)d_in[6];
  const float* rel  = (const float*)d_in[7];
  const float* ch   = (const float*)d_in[8];
  const float* ct   = (const float*)d_in[9];
  const float* bias = (const float*)d_in[10];

  float* out = (float*)d_out;                         // [B,N,D]
  float* fr  = out + (size_t)B_ * N_ * D_;            // [B,H,N,N]

  float* mask = (float*)d_ws;                         // [H,N,N]  512 KB
  f16* whh = (f16*)(mask + (size_t)H_ * N_ * N_);     // [512][512] f16
  f16* wvh = whh + (size_t)D_ * D_;
  f16* woh = wvh + (size_t)D_ * D_;

  hipLaunchKernelGGL(mask_kernel, dim3(H_ * N_), dim3(128), 0, stream,
                     ch, ct, bias, mask);
  hipLaunchKernelGGL(convert_w, dim3(256), dim3(256), 0, stream,
                     Whw, Wvw, Wow, whh, wvh, woh);
  hipLaunchKernelGGL(fused_attn, dim3(B_ * H_), dim3(256), 0, stream,
                     x, Whb, Wvb, rel, mask, whh, wvh, out, fr);
  hipLaunchKernelGGL(out_proj, dim3((B_ * N_) / 128), dim3(512), 0, stream,
                     woh, Wob, out);
}